// Round 11
// baseline (41.242 us; speedup 1.0000x reference)
//
#include <hip/hip_runtime.h>

// Problem constants (reference: B=256, L=512, N=4)
constexpr int B    = 256;
constexpr int NCOL = 2048;            // (l, n) columns: col = l*4 + n

#define MARGIN 1e-3f
#define LOG2E  1.4426950408889634f
#define LN2    0.6931471805599453

// ---- workspace layout (bytes); every location read is written every call ----
constexpr size_t OFF_SLAB   = 0;      // float slab[2048]    per-column loss (log2 units)
constexpr size_t OFF_CPAIRS = 8192;   // float cpairs[2048]  per-column C(c,2)

// ---------------------------------------------------------------------------
// Fused kernel: one block per (l,n) column.
// 1) Ballot compaction of the ~c=128 active rows into LDS (row order kept,
//    so compacted index order == row order).
// 2) BALANCED round-robin pair schedule (round-10 lesson: the t-anchored
//    triangle put 127 iters on wave0/SIMD0 and 0 on SIMDs 2,3):
//    pair (a, (a+d) mod c) for d in [1,(c-1)/2] covers each active pair once
//    with EQUAL trips per anchor. Wave w handles distance slice
//    d in [(wK)/4+1, ((w+1)K)/4]; lane l handles anchors l, l+64, l+128.
//    Even c: extra round d=c/2 for anchors a<c/2 (wave 3).
//    Orientation under wrap handled exactly: both x and the margin test flip.
// 3) Product-fold softplus: pp *= (2^xp + 1), one v_log per 8 elems
//    (8*|xp|max ~ 113 < 127: no f32 overflow).
// ---------------------------------------------------------------------------
__global__ __launch_bounds__(256) void col_pair_kernel(
    const float* __restrict__ preds,
    const float* __restrict__ targets,
    const int*   __restrict__ masks,
    float* __restrict__ slab,
    float* __restrict__ cpairs)
{
    const int col  = blockIdx.x;
    const int t    = threadIdx.x;
    const int lane = t & 63;
    const int wave = t >> 6;

    // --- compaction into LDS (strided gathers; inputs are cache-resident) ---
    const int   mv = masks[t * NCOL + col];
    const float uv = preds[t * NCOL + col] * LOG2E;
    const float tv = targets[t * NCOL + col];

    __shared__ float2 sc[256];
    __shared__ int    wcnt[4];
    __shared__ float  s4[4];

    const unsigned long long bal = __ballot(mv != 0);
    if (lane == 0) wcnt[wave] = __popcll(bal);
    __syncthreads();

    int basr = 0;
    #pragma unroll
    for (int w = 0; w < 4; ++w) basr += (w < wave) ? wcnt[w] : 0;
    const int c = wcnt[0] + wcnt[1] + wcnt[2] + wcnt[3];

    if (mv) {
        const int rank = basr + __popcll(bal & ((1ull << lane) - 1ull));
        sc[rank] = make_float2(uv, tv);
    }
    __syncthreads();

    // --- balanced pair loop ---
    const int K   = (c >= 1) ? ((c - 1) >> 1) : 0;
    const int dlo = (wave * K) / 4 + 1;        // wave-uniform (scalar)
    const int dhi = ((wave + 1) * K) / 4;

    float lg = 0.f;

    #pragma unroll
    for (int q = 0; q < 4; ++q) {
        const int a = lane + 64 * q;
        if (a < c) {
            const float2 av = sc[a];
            float pp = 1.f;
            for (int d = dlo; d <= dhi; ++d) {
                int b = a + d;
                const bool wr = (b >= c);
                b = wr ? b - c : b;
                const float2 bv = sc[b];
                const float x  = av.x - bv.x;
                const float td = av.y - bv.y;
                // wrapped pair is really (j=b_row < i=a_row): flip x and test
                const bool pos = wr ? (td < -MARGIN) : (td > MARGIN);
                const float xp = (pos != wr) ? -x : x;
                pp *= (__builtin_exp2f(xp) + 1.0f);
                if ((d & 7) == 7) { lg += __builtin_log2f(pp); pp = 1.f; }
            }
            lg += __builtin_log2f(pp);
        }
    }

    // even-c extra round: d = c/2, anchors a < c/2 (no wrap), on wave 3
    if (wave == 3 && c >= 2 && (c & 1) == 0) {
        const int hc = c >> 1;
        float pp = 1.f;
        #pragma unroll
        for (int q = 0; q < 2; ++q) {              // hc <= 128 -> a = lane, lane+64
            const int a = lane + 64 * q;
            if (a < hc) {
                const float2 av = sc[a];
                const float2 bv = sc[a + hc];
                const float x  = av.x - bv.x;
                const float td = av.y - bv.y;
                const float xp = (td > MARGIN) ? -x : x;
                pp *= (__builtin_exp2f(xp) + 1.0f);
            }
        }
        lg += __builtin_log2f(pp);                 // <= 2 factors, safe
    }

    // --- block reduction: wave shuffle -> LDS across 4 waves ---
    #pragma unroll
    for (int off = 32; off > 0; off >>= 1)
        lg += __shfl_down(lg, off, 64);
    if (lane == 0) s4[wave] = lg;
    __syncthreads();

    if (t == 0) {
        slab[col]   = s4[0] + s4[1] + s4[2] + s4[3];
        cpairs[col] = (float)((c * (c - 1)) / 2);  // exact in f32 (<= 32640)
    }
}

// ---------------------------------------------------------------------------
// Finalize: loss_n = sum_{col%4==n} slab[col];  cnt_n = sum cpairs[col];
// total = (1/4) * sum_n where(cnt>0, ln2 * loss_n / (cnt_n + EPS), 0)
// ---------------------------------------------------------------------------
__global__ __launch_bounds__(256) void finalize_kernel(
    const float* __restrict__ slab,
    const float* __restrict__ cpairs,
    float* __restrict__ out)
{
    const int t = threadIdx.x;
    double ls = 0.0, cs = 0.0;
    for (int q = t; q < NCOL; q += 256) {          // q%4 == t%4 (stride 256)
        ls += (double)slab[q];
        cs += (double)cpairs[q];
    }

    __shared__ double sl[256], sp[256], res[4];
    sl[t] = ls; sp[t] = cs;
    __syncthreads();

    if (t < 4) {
        double lsn = 0.0, csn = 0.0;
        for (int g = t; g < 256; g += 4) { lsn += sl[g]; csn += sp[g]; }
        res[t] = (csn > 0.0) ? (LN2 * lsn / (csn + 1e-8)) : 0.0;
    }
    __syncthreads();

    if (t == 0)
        out[0] = (float)((res[0] + res[1] + res[2] + res[3]) * 0.25);
}

extern "C" void kernel_launch(void* const* d_in, const int* in_sizes, int n_in,
                              void* d_out, int out_size, void* d_ws, size_t ws_size,
                              hipStream_t stream)
{
    const float* preds   = (const float*)d_in[0];
    const float* targets = (const float*)d_in[1];
    const int*   masks   = (const int*)d_in[2];   // jnp.bool_ arrives as int32
    float* out = (float*)d_out;

    char* ws = (char*)d_ws;
    float* slab   = (float*)(ws + OFF_SLAB);
    float* cpairs = (float*)(ws + OFF_CPAIRS);

    col_pair_kernel<<<NCOL, 256, 0, stream>>>(preds, targets, masks, slab, cpairs);
    finalize_kernel<<<1, 256, 0, stream>>>(slab, cpairs, out);
}